// Round 2
// baseline (601.721 us; speedup 1.0000x reference)
//
#include <hip/hip_runtime.h>
#include <hip/hip_bf16.h>

#define TT 2048
#define HD 2048
#define ID 2048
#define NE 8
#define BM 256
#define BN 128
#define BK 32
#define NKT 64            // K=2048 / BK

typedef __attribute__((ext_vector_type(8))) short short8;
typedef __attribute__((ext_vector_type(4))) float f4;

__device__ __forceinline__ unsigned short b16(float f){
  union { __hip_bfloat16 b; unsigned short u; } x;
  x.b = __float2bfloat16(f);
  return x.u;
}
__device__ __forceinline__ unsigned pk2(float lo, float hi){
  return (unsigned)b16(lo) | ((unsigned)b16(hi) << 16);
}
__device__ __forceinline__ float gelu_t(float x){
  float y = 0.7978845608028654f * (x + 0.044715f * x * x * x);
  float t = 1.0f - 2.0f / (__expf(2.0f * y) + 1.0f);
  return 0.5f * x * (1.0f + t);
}
__device__ __forceinline__ void glds16(const void* g, void* l){
  __builtin_amdgcn_global_load_lds(
      (const __attribute__((address_space(1))) unsigned*)g,
      (__attribute__((address_space(3))) unsigned*)l, 16, 0, 0);
}
__device__ __forceinline__ void softbar(){
  asm volatile("s_waitcnt lgkmcnt(0)" ::: "memory");
  __builtin_amdgcn_s_barrier();
  __builtin_amdgcn_sched_barrier(0);
}

// ---------------- X fp32 -> bf16 ----------------
__global__ void k_cvtx(const float* __restrict__ X, __hip_bfloat16* __restrict__ Xb){
  int i = blockIdx.x * 256 + threadIdx.x;          // 524288 threads x 8 elems
  const f4* src = (const f4*)X + (size_t)i * 2;
  f4 a = src[0], b = src[1];
  uint4 o = { pk2(a[0],a[1]), pk2(a[2],a[3]), pk2(b[0],b[1]), pk2(b[2],b[3]) };
  ((uint4*)Xb)[i] = o;
}

// ---------------- routing ----------------
__global__ void k_route(const float* __restrict__ lg, const float* __restrict__ sc,
                        int* __restrict__ rid, float* __restrict__ rw){
  int t = blockIdx.x * blockDim.x + threadIdx.x;
  if (t >= TT) return;
  float l[NE];
#pragma unroll
  for (int e = 0; e < NE; e++) l[e] = lg[t * NE + e];
  float mx = l[0];
#pragma unroll
  for (int e = 1; e < NE; e++) mx = fmaxf(mx, l[e]);
  float p[NE];
#pragma unroll
  for (int e = 0; e < NE; e++) p[e] = __expf(l[e] - mx);
  int i0 = 0; float b0 = l[0];
#pragma unroll
  for (int e = 1; e < NE; e++) if (l[e] > b0){ b0 = l[e]; i0 = e; }
  int i1 = -1; float b1 = -1e30f;
#pragma unroll
  for (int e = 0; e < NE; e++) if (e != i0 && l[e] > b1){ b1 = l[e]; i1 = e; }
  float p0 = p[i0], p1 = p[i1];
  float rn = p0 + p1; rn = (rn > 0.f) ? rn : 1.f;
  rw[t*2]   = p0 / rn * sc[i0];
  rw[t*2+1] = p1 / rn * sc[i1];
  rid[t*2]  = i0;
  rid[t*2+1]= i1;
}

// ---------------- deterministic per-expert compaction ----------------
__global__ void k_lists(const int* __restrict__ rid, const float* __restrict__ rw,
                        int* __restrict__ row_tok, float* __restrict__ row_w,
                        int* __restrict__ off){
  int lane = threadIdx.x;            // 64 threads
  int ids[64]; float wv[64];
#pragma unroll
  for (int i = 0; i < 64; i++) ids[i] = rid[i * 64 + lane];
#pragma unroll
  for (int i = 0; i < 64; i++) wv[i] = rw[i * 64 + lane];
  int cnt[NE];
#pragma unroll
  for (int e = 0; e < NE; e++) cnt[e] = 0;
#pragma unroll
  for (int i = 0; i < 64; i++){
#pragma unroll
    for (int e = 0; e < NE; e++)
      cnt[e] += __popcll(__ballot(ids[i] == e));
  }
  int offs[NE + 1]; offs[0] = 0;
#pragma unroll
  for (int e = 0; e < NE; e++) offs[e + 1] = offs[e] + cnt[e];
  if (lane == 0){
#pragma unroll
    for (int e = 0; e <= NE; e++) off[e] = offs[e];
  }
  int run[NE];
#pragma unroll
  for (int e = 0; e < NE; e++) run[e] = offs[e];
  unsigned long long ltm = (1ULL << lane) - 1ULL;
#pragma unroll
  for (int i = 0; i < 64; i++){
    int id = ids[i];
    int tok = (i * 64 + lane) >> 1;
#pragma unroll
    for (int e = 0; e < NE; e++){
      unsigned long long m = __ballot(id == e);
      if (id == e){
        int pos = run[e] + __popcll(m & ltm);
        row_tok[pos] = tok;
        row_w[pos]   = wv[i];
      }
      run[e] += __popcll(m);
    }
  }
}

// ---------------- gate+up grouped GEMM: 256x128 dual, BK=32, 2-phase pipeline ----------------
__global__ __launch_bounds__(512, 2)
void k_gateup(const __hip_bfloat16* __restrict__ Xb, const float* __restrict__ Wg,
              const float* __restrict__ Wu, const int* __restrict__ row_tok,
              const int* __restrict__ off, __hip_bfloat16* __restrict__ hbuf){
  __shared__ __align__(16) char sA[2][16384];   // [256 m][32 k] bf16, source-swizzled
  __shared__ __align__(16) char sBg[8192];      // [128 n][32 k] bf16, slot-swizzled
  __shared__ __align__(16) char sBu[8192];
  __shared__ int s_tok[BM];

  const int bid = blockIdx.x;
  const int e  = bid & 7;
  const int mt = (bid >> 3) & 15;
  const int nt = bid >> 7;
  const int o0 = off[e], o1 = off[e + 1];
  const int cnt = o1 - o0;
  if (mt * BM >= cnt) return;
  const int p0 = o0 + mt * BM;
  const int cntL = min(BM, cnt - mt * BM);
  const int tid = threadIdx.x;
  const int wid = tid >> 6, lane = tid & 63;

  if (tid < BM) s_tok[tid] = row_tok[min(p0 + tid, TT*2 - 1)];
  __syncthreads();

  // ---- A staging bases (global_load_lds, bf16 gather, source-side swizzle) ----
  const char* abase[2]; char* adst[2][2];
#pragma unroll
  for (int i = 0; i < 2; i++){
    int c = wid * 2 + i;                    // 16 chunks of 1KB
    int r = c * 16 + (lane >> 2);
    int slot = lane & 3;
    abase[i] = (const char*)Xb + (size_t)s_tok[r] * (HD * 2) + (((slot ^ (r & 3)) << 4));
    adst[0][i] = &sA[0][c * 1024];
    adst[1][i] = &sA[1][c * 1024];
  }
  // ---- B staging: thread -> one matrix, 4n x 4k block ----
  const int mat = tid >> 8, tt = tid & 255;
  const int bn0 = (tt & 31) * 4;
  const int bk0 = (tt >> 5) * 4;
  const float* bbase = (mat ? Wu : Wg) + (size_t)e * HD * ID + (size_t)bk0 * ID + (size_t)nt * BN + bn0;
  char* bdst = mat ? sBu : sBg;
  int bwoff[4];
#pragma unroll
  for (int j = 0; j < 4; j++){
    int n = bn0 + j;
    bwoff[j] = n * 64 + ((((bk0 >> 3) ^ (n & 3)) << 4) | ((bk0 & 4) << 1));
  }
  // ---- fragment read offsets ----
  const int wm = wid >> 1, wn = wid & 1;    // 4x2 waves, each 64x64 (dual)
  const int kg = lane >> 4, ln = lane & 15;
  int aoff[4], boff[4];
#pragma unroll
  for (int f = 0; f < 4; f++){
    int m = wm * 64 + f * 16 + ln;
    aoff[f] = m * 64 + ((kg ^ (m & 3)) << 4);
    int n = wn * 64 + f * 16 + ln;
    boff[f] = n * 64 + ((kg ^ (n & 3)) << 4);
  }

  f4 accg[4][4], accu[4][4];
#pragma unroll
  for (int a = 0; a < 4; a++)
#pragma unroll
    for (int b = 0; b < 4; b++){ accg[a][b] = f4{0,0,0,0}; accu[a][b] = f4{0,0,0,0}; }

  // ---- prologue: prefetch tile 0 ----
#pragma unroll
  for (int i = 0; i < 2; i++) glds16(abase[i], adst[0][i]);
  f4 pb0 = bbase[0 * (ID/4)], pb1, pb2, pb3;
  { const f4* bp = (const f4*)bbase; pb0 = bp[0]; pb1 = bp[ID/4]; pb2 = bp[2*(ID/4)]; pb3 = bp[3*(ID/4)]; }

  for (int kt = 0; kt < NKT; ++kt){
    __syncthreads();                                   // drains vmcnt -> tile kt landed
    const int par = kt & 1;
    if (kt + 1 < NKT){
#pragma unroll
      for (int i = 0; i < 2; i++) glds16(abase[i] + (kt + 1) * (BK * 2), adst[par ^ 1][i]);
    }
    // cvt + write B(kt)
#pragma unroll
    for (int j = 0; j < 4; j++){
      *(uint2*)(bdst + bwoff[j]) = uint2{ pk2(pb0[j], pb1[j]), pk2(pb2[j], pb3[j]) };
    }
    if (kt + 1 < NKT){
      const f4* bp = (const f4*)(bbase + (size_t)(kt + 1) * BK * ID);
      pb0 = bp[0]; pb1 = bp[ID/4]; pb2 = bp[2*(ID/4)]; pb3 = bp[3*(ID/4)];
    }
    softbar();                                         // lgkm only: prefetch stays in flight
    short8 af[4];
#pragma unroll
    for (int f = 0; f < 4; f++) af[f] = *(const short8*)(&sA[par][0] + aoff[f]);
#pragma unroll
    for (int fn = 0; fn < 4; fn++){
      short8 bg = *(const short8*)(sBg + boff[fn]);
      short8 bu = *(const short8*)(sBu + boff[fn]);
#pragma unroll
      for (int fm = 0; fm < 4; fm++){
        accg[fm][fn] = __builtin_amdgcn_mfma_f32_16x16x32_bf16(af[fm], bg, accg[fm][fn], 0, 0, 0);
        accu[fm][fn] = __builtin_amdgcn_mfma_f32_16x16x32_bf16(af[fm], bu, accu[fm][fn], 0, 0, 0);
      }
    }
  }
  // ---- epilogue: h = gelu(g)*u -> bf16 ----
#pragma unroll
  for (int fm = 0; fm < 4; fm++){
#pragma unroll
    for (int r = 0; r < 4; r++){
      int row = wm * 64 + fm * 16 + (lane >> 4) * 4 + r;
      if (row < cntL){
        size_t base = (size_t)(p0 + row) * ID + (size_t)nt * BN + wn * 64 + (lane & 15);
#pragma unroll
        for (int fn = 0; fn < 4; fn++){
          float g = accg[fm][fn][r];
          float u = accu[fm][fn][r];
          hbuf[base + fn * 16] = __float2bfloat16(gelu_t(g) * u);
        }
      }
    }
  }
}

// ---------------- down GEMM + weighted atomic scatter: 256x128, BK=32 ----------------
__global__ __launch_bounds__(512, 2)
void k_down(const __hip_bfloat16* __restrict__ hbuf, const float* __restrict__ Wd,
            const int* __restrict__ row_tok, const float* __restrict__ row_w,
            const int* __restrict__ off, float* __restrict__ out){
  __shared__ __align__(16) char sA[2][16384];
  __shared__ __align__(16) char sB[8192];
  __shared__ int s_tok[BM];
  __shared__ float s_w[BM];

  const int bid = blockIdx.x;
  const int e  = bid & 7;
  const int mt = (bid >> 3) & 15;
  const int nt = bid >> 7;
  const int o0 = off[e], o1 = off[e + 1];
  const int cnt = o1 - o0;
  if (mt * BM >= cnt) return;
  const int p0 = o0 + mt * BM;
  const int cntL = min(BM, cnt - mt * BM);
  const int tid = threadIdx.x;
  const int wid = tid >> 6, lane = tid & 63;

  if (tid < BM){
    int p = min(p0 + tid, TT*2 - 1);
    s_tok[tid] = row_tok[p];
    s_w[tid]   = row_w[p];
  }
  __syncthreads();

  const char* abase[2]; char* adst[2][2];
#pragma unroll
  for (int i = 0; i < 2; i++){
    int c = wid * 2 + i;
    int r = c * 16 + (lane >> 2);
    int slot = lane & 3;
    int p = min(p0 + r, TT*2 - 1);
    abase[i] = (const char*)hbuf + (size_t)p * (ID * 2) + (((slot ^ (r & 3)) << 4));
    adst[0][i] = &sA[0][c * 1024];
    adst[1][i] = &sA[1][c * 1024];
  }
  // B: 512 threads, one matrix: 4n x 4k each over [32k][128n]
  const int bn0 = (tid & 31) * 4;
  const int bk0 = (tid >> 5) * 4;            // 0..60? tid>>5 in [0,16) -> bk0 in [0,64) -- need [0,32): use &7
  const int bk = (bk0 & 28);                 // (tid>>5)&7 *4
  const int half = (tid >> 8);               // 0/1: duplicate work split over n? no: split n range
  // Re-map: threads 0..255 cover n 0..127 x k 0..28 step4 (4x4 each); threads 256..511 idle for B? 
  // Instead: all 512 threads: n0 = (tid & 63) * 2, k0 = (tid >> 6) * 4  -> 2n x 4k each
  const int n0 = (tid & 63) * 2;
  const int k0 = (tid >> 6) * 4;             // 0..28
  const float* bbase = Wd + (size_t)e * ID * HD + (size_t)k0 * HD + (size_t)nt * BN + n0;
  int bwoff[2];
#pragma unroll
  for (int j = 0; j < 2; j++){
    int n = n0 + j;
    bwoff[j] = n * 64 + ((((k0 >> 3) ^ (n & 3)) << 4) | ((k0 & 4) << 1));
  }

  const int wm = wid >> 1, wn = wid & 1;
  const int kg = lane >> 4, ln = lane & 15;
  int aoff[4], boff[4];
#pragma unroll
  for (int f = 0; f < 4; f++){
    int m = wm * 64 + f * 16 + ln;
    aoff[f] = m * 64 + ((kg ^ (m & 3)) << 4);
    int n = wn * 64 + f * 16 + ln;
    boff[f] = n * 64 + ((kg ^ (n & 3)) << 4);
  }

  f4 acc[4][4];
#pragma unroll
  for (int a = 0; a < 4; a++)
#pragma unroll
    for (int b = 0; b < 4; b++) acc[a][b] = f4{0,0,0,0};

#pragma unroll
  for (int i = 0; i < 2; i++) glds16(abase[i], adst[0][i]);
  f4 q0, q1;   // 2 floats x 4 rows = use two f4? rows strided HD: load 2 floats per row -> float2
  float2 r0, r1, r2, r3;
  { const float2* bp = (const float2*)bbase;
    r0 = bp[0]; r1 = bp[HD/2]; r2 = bp[HD]; r3 = bp[3*(HD/2)]; }
  (void)q0; (void)q1;

  for (int kt = 0; kt < NKT; ++kt){
    __syncthreads();
    const int par = kt & 1;
    if (kt + 1 < NKT){
#pragma unroll
      for (int i = 0; i < 2; i++) glds16(abase[i] + (kt + 1) * (BK * 2), adst[par ^ 1][i]);
    }
#pragma unroll
    for (int j = 0; j < 2; j++){
      float v0 = j ? r0.y : r0.x, v1 = j ? r1.y : r1.x;
      float v2 = j ? r2.y : r2.x, v3 = j ? r3.y : r3.x;
      *(uint2*)(sB + bwoff[j]) = uint2{ pk2(v0, v1), pk2(v2, v3) };
    }
    if (kt + 1 < NKT){
      const float2* bp = (const float2*)(bbase + (size_t)(kt + 1) * BK * HD);
      r0 = bp[0]; r1 = bp[HD/2]; r2 = bp[HD]; r3 = bp[3*(HD/2)];
    }
    softbar();
    short8 af[4];
#pragma unroll
    for (int f = 0; f < 4; f++) af[f] = *(const short8*)(&sA[par][0] + aoff[f]);
#pragma unroll
    for (int fn = 0; fn < 4; fn++){
      short8 bf = *(const short8*)(sB + boff[fn]);
#pragma unroll
      for (int fm = 0; fm < 4; fm++)
        acc[fm][fn] = __builtin_amdgcn_mfma_f32_16x16x32_bf16(af[fm], bf, acc[fm][fn], 0, 0, 0);
    }
  }
#pragma unroll
  for (int fm = 0; fm < 4; fm++){
#pragma unroll
    for (int r = 0; r < 4; r++){
      int row = wm * 64 + fm * 16 + (lane >> 4) * 4 + r;
      if (row < cntL){
        int tok = s_tok[row];
        float w = s_w[row];
        float* ob = out + (size_t)tok * HD + (size_t)nt * BN + wn * 64 + (lane & 15);
#pragma unroll
        for (int fn = 0; fn < 4; fn++)
          atomicAdd(ob + fn * 16, acc[fm][fn][r] * w);
      }
    }
  }
}

extern "C" void kernel_launch(void* const* d_in, const int* in_sizes, int n_in,
                              void* d_out, int out_size, void* d_ws, size_t ws_size,
                              hipStream_t stream){
  (void)in_sizes; (void)n_in; (void)out_size; (void)ws_size;
  const float* X  = (const float*)d_in[0];
  const float* RL = (const float*)d_in[1];
  const float* SC = (const float*)d_in[2];
  const float* Wg = (const float*)d_in[3];
  const float* Wu = (const float*)d_in[4];
  const float* Wd = (const float*)d_in[5];
  float* out = (float*)d_out;

  char* ws = (char*)d_ws;
  int*   rid     = (int*)(ws);
  float* rw      = (float*)(ws + 16384);
  int*   row_tok = (int*)(ws + 32768);
  float* row_w   = (float*)(ws + 49152);
  int*   off     = (int*)(ws + 65536);
  __hip_bfloat16* hbuf = (__hip_bfloat16*)(ws + 66560);          // 4096x2048 bf16 = 16 MiB
  __hip_bfloat16* Xb   = (__hip_bfloat16*)(ws + 66560 + (size_t)TT*2*ID*2);  // 8 MiB

  hipMemsetAsync(d_out, 0, (size_t)TT * HD * sizeof(float), stream);
  k_cvtx <<<2048, 256, 0, stream>>>(X, Xb);
  k_route<<<TT / 256, 256, 0, stream>>>(RL, SC, rid, rw);
  k_lists<<<1, 64, 0, stream>>>(rid, rw, row_tok, row_w, off);
  k_gateup<<<2048, 512, 0, stream>>>(Xb, Wg, Wu, row_tok, off, hbuf);
  k_down<<<2048, 512, 0, stream>>>(hbuf, Wd, row_tok, row_w, off, out);
}

// Round 3
// 398.992 us; speedup vs baseline: 1.5081x; 1.5081x over previous
//
#include <hip/hip_runtime.h>
#include <hip/hip_bf16.h>

#define TT 2048
#define HD 2048
#define ID 2048
#define NE 8

typedef __attribute__((ext_vector_type(8))) short short8;
typedef __attribute__((ext_vector_type(4))) float f4;

__device__ __forceinline__ unsigned short b16(float f){
  union { __hip_bfloat16 b; unsigned short u; } x;
  x.b = __float2bfloat16(f);
  return x.u;
}
__device__ __forceinline__ unsigned pk2(float lo, float hi){
  return (unsigned)b16(lo) | ((unsigned)b16(hi) << 16);
}
__device__ __forceinline__ float gelu_t(float x){
  float y = 0.7978845608028654f * (x + 0.044715f * x * x * x);
  float t = 1.0f - 2.0f / (__expf(2.0f * y) + 1.0f);
  return 0.5f * x * (1.0f + t);
}
__device__ __forceinline__ void glds16(const void* g, void* l){
  __builtin_amdgcn_global_load_lds(
      (const __attribute__((address_space(1))) unsigned*)g,
      (__attribute__((address_space(3))) unsigned*)l, 16, 0, 0);
}
__device__ __forceinline__ void softbar(){
  asm volatile("s_waitcnt lgkmcnt(0)" ::: "memory");
  __builtin_amdgcn_s_barrier();
  __builtin_amdgcn_sched_barrier(0);
}
__device__ __forceinline__ int swzB(int n){ return (((n >> 2) & 7) ^ ((n & 3) << 1)) & 7; }

// ---------------- X fp32 -> bf16 ----------------
__global__ void k_cvtx(const float* __restrict__ X, __hip_bfloat16* __restrict__ Xb){
  int i = blockIdx.x * 256 + threadIdx.x;
  const f4* src = (const f4*)X + (size_t)i * 2;
  f4 a = src[0], b = src[1];
  uint4 o = { pk2(a[0],a[1]), pk2(a[2],a[3]), pk2(b[0],b[1]), pk2(b[2],b[3]) };
  ((uint4*)Xb)[i] = o;
}

// ---------------- routing ----------------
__global__ void k_route(const float* __restrict__ lg, const float* __restrict__ sc,
                        int* __restrict__ rid, float* __restrict__ rw){
  int t = blockIdx.x * blockDim.x + threadIdx.x;
  if (t >= TT) return;
  float l[NE];
#pragma unroll
  for (int e = 0; e < NE; e++) l[e] = lg[t * NE + e];
  float mx = l[0];
#pragma unroll
  for (int e = 1; e < NE; e++) mx = fmaxf(mx, l[e]);
  float p[NE];
#pragma unroll
  for (int e = 0; e < NE; e++) p[e] = __expf(l[e] - mx);
  int i0 = 0; float b0 = l[0];
#pragma unroll
  for (int e = 1; e < NE; e++) if (l[e] > b0){ b0 = l[e]; i0 = e; }
  int i1 = -1; float b1 = -1e30f;
#pragma unroll
  for (int e = 0; e < NE; e++) if (e != i0 && l[e] > b1){ b1 = l[e]; i1 = e; }
  float p0 = p[i0], p1 = p[i1];
  float rn = p0 + p1; rn = (rn > 0.f) ? rn : 1.f;
  rw[t*2]   = p0 / rn * sc[i0];
  rw[t*2+1] = p1 / rn * sc[i1];
  rid[t*2]  = i0;
  rid[t*2+1]= i1;
}

// ---------------- deterministic per-expert compaction ----------------
__global__ void k_lists(const int* __restrict__ rid, const float* __restrict__ rw,
                        int* __restrict__ row_tok, float* __restrict__ row_w,
                        int* __restrict__ off){
  int lane = threadIdx.x;            // 64 threads
  int ids[64]; float wv[64];
#pragma unroll
  for (int i = 0; i < 64; i++) ids[i] = rid[i * 64 + lane];
#pragma unroll
  for (int i = 0; i < 64; i++) wv[i] = rw[i * 64 + lane];
  int cnt[NE];
#pragma unroll
  for (int e = 0; e < NE; e++) cnt[e] = 0;
#pragma unroll
  for (int i = 0; i < 64; i++){
#pragma unroll
    for (int e = 0; e < NE; e++)
      cnt[e] += __popcll(__ballot(ids[i] == e));
  }
  int offs[NE + 1]; offs[0] = 0;
#pragma unroll
  for (int e = 0; e < NE; e++) offs[e + 1] = offs[e] + cnt[e];
  if (lane == 0){
#pragma unroll
    for (int e = 0; e <= NE; e++) off[e] = offs[e];
  }
  int run[NE];
#pragma unroll
  for (int e = 0; e < NE; e++) run[e] = offs[e];
  unsigned long long ltm = (1ULL << lane) - 1ULL;
#pragma unroll
  for (int i = 0; i < 64; i++){
    int id = ids[i];
    int tok = (i * 64 + lane) >> 1;
#pragma unroll
    for (int e = 0; e < NE; e++){
      unsigned long long m = __ballot(id == e);
      if (id == e){
        int pos = run[e] + __popcll(m & ltm);
        row_tok[pos] = tok;
        row_w[pos]   = wv[i];
      }
      run[e] += __popcll(m);
    }
  }
}

// -------- gate+up grouped GEMM: 128(m) x 64(n) dual tile, BK=64, 3 blocks/CU --------
__global__ __launch_bounds__(256, 3)
void k_gateup(const __hip_bfloat16* __restrict__ Xb, const float* __restrict__ Wg,
              const float* __restrict__ Wu, const int* __restrict__ row_tok,
              const int* __restrict__ off, __hip_bfloat16* __restrict__ hbuf){
  __shared__ __align__(16) char sA[2][16384];   // [128 m][64 k] bf16, slot^=(m&7)
  __shared__ __align__(16) char sBg[8192];      // [64 n][64 k] bf16, slot^=swzB(n)
  __shared__ __align__(16) char sBu[8192];
  __shared__ int s_tok[128];

  const int bid = blockIdx.x;           // 2048 = 8e x 8mt x 32nt ; e==XCD pin
  const int e  = bid & 7;
  const int mt = (bid >> 3) & 7;
  const int nt = bid >> 6;              // 0..31
  const int o0 = off[e], cnt = off[e + 1] - o0;
  if (mt * 128 >= cnt) return;
  const int p0 = o0 + mt * 128;
  const int cntL = min(128, cnt - mt * 128);
  const int tid = threadIdx.x;
  const int wid = tid >> 6, lane = tid & 63;

  if (tid < 128) s_tok[tid] = row_tok[min(p0 + tid, TT*2 - 1)];
  __syncthreads();

  // A staging sources: chunk c = wid*4+i (1KB), lane l -> row c*8+(l>>3), slot l&7
  const char* asrc[4];
#pragma unroll
  for (int i = 0; i < 4; i++){
    int c = wid * 4 + i;
    int r = c * 8 + (lane >> 3);
    asrc[i] = (const char*)Xb + (size_t)s_tok[r] * (HD * 2)
            + ((((lane & 7) ^ (lane >> 3)) & 7) << 4);
  }
  // B staging: thread -> 4 k-rows x 4 n
  const int n0 = (tid & 15) * 4;
  const int k0 = (tid >> 4) * 4;        // 0..60
  const size_t wb = (size_t)e * HD * ID + (size_t)k0 * ID + (size_t)nt * 64 + n0;
  const float* gsrc = Wg + wb;
  const float* usrc = Wu + wb;
  int bw[4];
#pragma unroll
  for (int j = 0; j < 4; j++)
    bw[j] = (n0 + j) * 128 + ((((k0 >> 3) ^ (tid & 7) ^ (j << 1)) & 7) << 4) + ((k0 & 4) << 1);

  // fragment read offsets
  const int wm = wid >> 1, wn = wid & 1;     // 2x2 waves: 64 rows x 32 cols (dual)
  const int kg = lane >> 4, ln = lane & 15;
  int aoff[2][4], boff[2][2];
#pragma unroll
  for (int ks = 0; ks < 2; ks++){
    int qs = ks * 4 + kg;
#pragma unroll
    for (int f = 0; f < 4; f++){
      int m = wm * 64 + f * 16 + ln;
      aoff[ks][f] = m * 128 + (((qs ^ (ln & 7)) & 7) << 4);
    }
#pragma unroll
    for (int f = 0; f < 2; f++){
      int n = wn * 32 + f * 16 + ln;
      boff[ks][f] = n * 128 + (((qs ^ swzB(n)) & 7) << 4);
    }
  }

  f4 accg[4][2], accu[4][2];
#pragma unroll
  for (int a = 0; a < 4; a++)
#pragma unroll
    for (int b = 0; b < 2; b++){ accg[a][b] = f4{0,0,0,0}; accu[a][b] = f4{0,0,0,0}; }

  // prologue: A(0) -> sA[0]; B(0) -> regs
#pragma unroll
  for (int i = 0; i < 4; i++) glds16(asrc[i], &sA[0][(wid * 4 + i) * 1024]);
  f4 g0, g1, g2, g3, u0, u1, u2, u3;
  { const f4* p = (const f4*)gsrc; g0 = p[0]; g1 = p[ID/4]; g2 = p[ID/2]; g3 = p[3*ID/4];
    const f4* q = (const f4*)usrc; u0 = q[0]; u1 = q[ID/4]; u2 = q[ID/2]; u3 = q[3*ID/4]; }

  for (int kt = 0; kt < 32; ++kt){
    softbar();                                   // bar1: prev compute done reading LDS
    if (kt + 1 < 32){
      char* dst = &sA[(kt + 1) & 1][0] + (wid * 4) * 1024;
#pragma unroll
      for (int i = 0; i < 4; i++) glds16(asrc[i] + (size_t)(kt + 1) * 128, dst + i * 1024);
    }
    // ds_write B(kt): compiler's exact vmcnt here drains B(kt) regs AND A(kt) glds
#pragma unroll
    for (int j = 0; j < 4; j++){
      *(uint2*)(sBg + bw[j]) = uint2{ pk2(g0[j], g1[j]), pk2(g2[j], g3[j]) };
      *(uint2*)(sBu + bw[j]) = uint2{ pk2(u0[j], u1[j]), pk2(u2[j], u3[j]) };
    }
    softbar();                                   // bar2: A landed (per-wave wait + barrier), B visible
    if (kt + 1 < 32){
      const f4* p = (const f4*)(gsrc + (size_t)(kt + 1) * 64 * ID);
      g0 = p[0]; g1 = p[ID/4]; g2 = p[ID/2]; g3 = p[3*ID/4];
      const f4* q = (const f4*)(usrc + (size_t)(kt + 1) * 64 * ID);
      u0 = q[0]; u1 = q[ID/4]; u2 = q[ID/2]; u3 = q[3*ID/4];
    }
    const char* A = &sA[kt & 1][0];
#pragma unroll
    for (int ks = 0; ks < 2; ks++){
      short8 af[4];
#pragma unroll
      for (int f = 0; f < 4; f++) af[f] = *(const short8*)(A + aoff[ks][f]);
#pragma unroll
      for (int fn = 0; fn < 2; fn++){
        short8 bg = *(const short8*)(sBg + boff[ks][fn]);
        short8 bu = *(const short8*)(sBu + boff[ks][fn]);
#pragma unroll
        for (int fm = 0; fm < 4; fm++){
          accg[fm][fn] = __builtin_amdgcn_mfma_f32_16x16x32_bf16(af[fm], bg, accg[fm][fn], 0, 0, 0);
          accu[fm][fn] = __builtin_amdgcn_mfma_f32_16x16x32_bf16(af[fm], bu, accu[fm][fn], 0, 0, 0);
        }
      }
    }
  }
  // epilogue: h = gelu(g)*u -> bf16
#pragma unroll
  for (int fm = 0; fm < 4; fm++){
#pragma unroll
    for (int r = 0; r < 4; r++){
      int row = wm * 64 + fm * 16 + (lane >> 4) * 4 + r;
      if (row < cntL){
        size_t base = (size_t)(p0 + row) * ID + (size_t)nt * 64 + wn * 32 + ln;
#pragma unroll
        for (int fn = 0; fn < 2; fn++){
          float g = accg[fm][fn][r];
          float u = accu[fm][fn][r];
          hbuf[base + fn * 16] = __float2bfloat16(gelu_t(g) * u);
        }
      }
    }
  }
}

// -------- down GEMM + weighted atomic scatter: 128(m) x 128(n), BK=64, 3 blocks/CU --------
__global__ __launch_bounds__(256, 3)
void k_down(const __hip_bfloat16* __restrict__ hbuf, const float* __restrict__ Wd,
            const int* __restrict__ row_tok, const float* __restrict__ row_w,
            const int* __restrict__ off, float* __restrict__ out){
  __shared__ __align__(16) char sA[2][16384];   // [128 m][64 k] bf16
  __shared__ __align__(16) char sB[16384];      // [128 n][64 k] bf16
  __shared__ int s_tok[128];
  __shared__ float s_w[128];

  const int bid = blockIdx.x;           // 1024 = 8e x 8mt x 16nt
  const int e  = bid & 7;
  const int mt = (bid >> 3) & 7;
  const int nt = bid >> 6;              // 0..15
  const int o0 = off[e], cnt = off[e + 1] - o0;
  if (mt * 128 >= cnt) return;
  const int p0 = o0 + mt * 128;
  const int cntL = min(128, cnt - mt * 128);
  const int tid = threadIdx.x;
  const int wid = tid >> 6, lane = tid & 63;

  if (tid < 128){
    int p = min(p0 + tid, TT*2 - 1);
    s_tok[tid] = row_tok[p];
    s_w[tid]   = row_w[p];
  }
  __syncthreads();

  const char* asrc[4];
#pragma unroll
  for (int i = 0; i < 4; i++){
    int c = wid * 4 + i;
    int r = c * 8 + (lane >> 3);
    int p = min(p0 + r, TT*2 - 1);
    asrc[i] = (const char*)hbuf + (size_t)p * (ID * 2)
            + ((((lane & 7) ^ (lane >> 3)) & 7) << 4);
  }
  // B staging: thread -> 8 k-rows x 4 n
  const int n0 = (tid & 31) * 4;
  const int k0 = (tid >> 5) * 8;        // 0..56
  const float* bsrc = Wd + (size_t)e * ID * HD + (size_t)k0 * HD + (size_t)nt * 128 + n0;
  int bw[4];
#pragma unroll
  for (int j = 0; j < 4; j++)
    bw[j] = (n0 + j) * 128 + ((((k0 >> 3) ^ (tid & 7) ^ (j << 1)) & 7) << 4);

  const int wm = wid >> 1, wn = wid & 1;     // 2x2 waves: 64 x 64
  const int kg = lane >> 4, ln = lane & 15;
  int aoff[2][4], boff[2][4];
#pragma unroll
  for (int ks = 0; ks < 2; ks++){
    int qs = ks * 4 + kg;
#pragma unroll
    for (int f = 0; f < 4; f++){
      int m = wm * 64 + f * 16 + ln;
      aoff[ks][f] = m * 128 + (((qs ^ (ln & 7)) & 7) << 4);
      int n = wn * 64 + f * 16 + ln;
      boff[ks][f] = n * 128 + (((qs ^ swzB(n)) & 7) << 4);
    }
  }

  f4 acc[4][4];
#pragma unroll
  for (int a = 0; a < 4; a++)
#pragma unroll
    for (int b = 0; b < 4; b++) acc[a][b] = f4{0,0,0,0};

#pragma unroll
  for (int i = 0; i < 4; i++) glds16(asrc[i], &sA[0][(wid * 4 + i) * 1024]);
  f4 r0, r1, r2, r3, r4, r5, r6, r7;
  { const f4* p = (const f4*)bsrc;
    r0 = p[0]; r1 = p[HD/4]; r2 = p[HD/2]; r3 = p[3*HD/4];
    r4 = p[HD]; r5 = p[5*HD/4]; r6 = p[3*HD/2]; r7 = p[7*HD/4]; }

  for (int kt = 0; kt < 32; ++kt){
    softbar();                                   // bar1
    if (kt + 1 < 32){
      char* dst = &sA[(kt + 1) & 1][0] + (wid * 4) * 1024;
#pragma unroll
      for (int i = 0; i < 4; i++) glds16(asrc[i] + (size_t)(kt + 1) * 128, dst + i * 1024);
    }
#pragma unroll
    for (int j = 0; j < 4; j++){
      *(uint4*)(sB + bw[j]) = uint4{ pk2(r0[j], r1[j]), pk2(r2[j], r3[j]),
                                     pk2(r4[j], r5[j]), pk2(r6[j], r7[j]) };
    }
    softbar();                                   // bar2
    if (kt + 1 < 32){
      const f4* p = (const f4*)(bsrc + (size_t)(kt + 1) * 64 * HD);
      r0 = p[0]; r1 = p[HD/4]; r2 = p[HD/2]; r3 = p[3*HD/4];
      r4 = p[HD]; r5 = p[5*HD/4]; r6 = p[3*HD/2]; r7 = p[7*HD/4];
    }
    const char* A = &sA[kt & 1][0];
#pragma unroll
    for (int ks = 0; ks < 2; ks++){
      short8 af[4];
#pragma unroll
      for (int f = 0; f < 4; f++) af[f] = *(const short8*)(A + aoff[ks][f]);
#pragma unroll
      for (int fn = 0; fn < 4; fn++){
        short8 bf = *(const short8*)(sB + boff[ks][fn]);
#pragma unroll
        for (int fm = 0; fm < 4; fm++)
          acc[fm][fn] = __builtin_amdgcn_mfma_f32_16x16x32_bf16(af[fm], bf, acc[fm][fn], 0, 0, 0);
      }
    }
  }
  // epilogue: out[tok] += w * y   (2 commutative fp32 adds per element, deterministic)
#pragma unroll
  for (int fm = 0; fm < 4; fm++){
#pragma unroll
    for (int r = 0; r < 4; r++){
      int row = wm * 64 + fm * 16 + (lane >> 4) * 4 + r;
      if (row < cntL){
        int tok = s_tok[row];
        float w = s_w[row];
        float* ob = out + (size_t)tok * HD + (size_t)nt * 128 + wn * 64 + ln;
#pragma unroll
        for (int fn = 0; fn < 4; fn++)
          atomicAdd(ob + fn * 16, acc[fm][fn][r] * w);
      }
    }
  }
}

extern "C" void kernel_launch(void* const* d_in, const int* in_sizes, int n_in,
                              void* d_out, int out_size, void* d_ws, size_t ws_size,
                              hipStream_t stream){
  (void)in_sizes; (void)n_in; (void)out_size; (void)ws_size;
  const float* X  = (const float*)d_in[0];
  const float* RL = (const float*)d_in[1];
  const float* SC = (const float*)d_in[2];
  const float* Wg = (const float*)d_in[3];
  const float* Wu = (const float*)d_in[4];
  const float* Wd = (const float*)d_in[5];
  float* out = (float*)d_out;

  char* ws = (char*)d_ws;
  int*   rid     = (int*)(ws);
  float* rw      = (float*)(ws + 16384);
  int*   row_tok = (int*)(ws + 32768);
  float* row_w   = (float*)(ws + 49152);
  int*   off     = (int*)(ws + 65536);
  __hip_bfloat16* hbuf = (__hip_bfloat16*)(ws + 66560);                      // 16 MiB
  __hip_bfloat16* Xb   = (__hip_bfloat16*)(ws + 66560 + (size_t)TT*2*ID*2);  // 8 MiB

  hipMemsetAsync(d_out, 0, (size_t)TT * HD * sizeof(float), stream);
  k_cvtx <<<2048, 256, 0, stream>>>(X, Xb);
  k_route<<<TT / 256, 256, 0, stream>>>(RL, SC, rid, rw);
  k_lists<<<1, 64, 0, stream>>>(rid, rw, row_tok, row_w, off);
  k_gateup<<<2048, 256, 0, stream>>>(Xb, Wg, Wu, row_tok, off, hbuf);
  k_down<<<1024, 256, 0, stream>>>(hbuf, Wd, row_tok, row_w, off, out);
}